// Round 10
// baseline (83.794 us; speedup 1.0000x reference)
//
#include <hip/hip_runtime.h>
#include <stdint.h>

#define HEADS 4
#define NEG_SLOPE 0.2f
#define MB 64      // rows per block in projection kernel

typedef _Float16 f16;
typedef f16 f16x8 __attribute__((ext_vector_type(8)));
typedef f16 f16x4 __attribute__((ext_vector_type(4)));
typedef float f32x4 __attribute__((ext_vector_type(4)));
typedef unsigned int u32x4 __attribute__((ext_vector_type(4)));

// swizzled LDS byte offset for a [rows][128] f16 tile (256 B rows):
// XOR row bits into the 16B-slot bits to kill the 16-way bank conflict
#define SWZ(row, kb) (((row) << 8) + ((kb) ^ (((row) & 7) << 4)))

// ---- pre-kernel: w (f32 [K=128][N=128]) -> wt (f16 [N=128][K=128]) ----
__global__ __launch_bounds__(256) void wt_kernel(const float* __restrict__ w,
                                                 f16* __restrict__ wt) {
    __shared__ f16 tl[16][136];  // +8 pad
    const int b = blockIdx.x, t = threadIdx.x;
    for (int i = t; i < 2048; i += 256) {   // 128 k-rows x 16 cols of this slice
        int k = i >> 4, nl = i & 15;
        tl[nl][k] = (f16)w[k * 128 + b * 16 + nl];
    }
    __syncthreads();
    {
        int nl = t >> 4, kc = t & 15;       // 16 rows x 16 chunks = 256 threads
        f16x8 v = *(const f16x8*)&tl[nl][kc * 8];
        *(f16x8*)(wt + (b * 16 + nl) * 128 + kc * 8) = v;
    }
}

// ---- projection: xp = f16(x) @ f16(w) via MFMA + a_src/a_dst logit dots ----
// xp is written in 4-slice layout: [4 slices of 32 cols][node][32] f16 (64 B
// rows, one full cache line per edge-gather). Slice s == head s.
__global__ __launch_bounds__(256) void gat_proj_mfma(
    const float* __restrict__ x, const f16* __restrict__ wt,
    const float* __restrict__ att, f16* __restrict__ xp,
    float* __restrict__ a_src, float* __restrict__ a_dst, int n) {
    __shared__ unsigned char lds[32768];
    __shared__ float att_l[256];
    const int t = threadIdx.x;
    const int node0 = blockIdx.x * MB;
    const int lane = t & 63;
    const int wv = t >> 6;

    att_l[t] = att[t];

    // A-frags: row = node0 + wv*16 + (lane&15); kt-frag cols kt*32+(lane>>4)*8..+8
    const int arow = node0 + wv * 16 + (lane & 15);
    const bool rowok = arow < n;
    const float* xr = x + (size_t)arow * 128 + (lane >> 4) * 8;
    f16x8 afr[4];
#pragma unroll
    for (int kt = 0; kt < 4; kt++) {
        float4 a = make_float4(0.f, 0.f, 0.f, 0.f), b = a;
        if (rowok) {
            a = *(const float4*)(xr + kt * 32);
            b = *(const float4*)(xr + kt * 32 + 4);
        }
        f16x8 hv;
        hv[0] = (f16)a.x; hv[1] = (f16)a.y; hv[2] = (f16)a.z; hv[3] = (f16)a.w;
        hv[4] = (f16)b.x; hv[5] = (f16)b.y; hv[6] = (f16)b.z; hv[7] = (f16)b.w;
        afr[kt] = hv;
    }

    // stage wt (f16, [N][K]) into swizzled LDS
    for (int i = t; i < 2048; i += 256) {
        int row = i >> 4, kc = i & 15;
        uint4 v = *(const uint4*)(wt + row * 128 + kc * 8);
        *(uint4*)(lds + SWZ(row, kc * 16)) = v;
    }
    __syncthreads();

    // MFMA: wave wv owns rows wv*16..+15 (1 M-frag), all 128 cols
    f32x4 acc[8];
#pragma unroll
    for (int nf = 0; nf < 8; nf++) acc[nf] = (f32x4){0.f, 0.f, 0.f, 0.f};

#pragma unroll
    for (int kt = 0; kt < 4; kt++) {
        const int kb = kt * 64 + (lane >> 4) * 16;
#pragma unroll
        for (int nf = 0; nf < 8; nf++) {
            f16x8 bfr = *(const f16x8*)(lds + SWZ(nf * 16 + (lane & 15), kb));
            acc[nf] = __builtin_amdgcn_mfma_f32_16x16x32_f16(afr[kt], bfr, acc[nf], 0, 0, 0);
        }
    }

    // repack accumulators (f16) into the (now-free) wt LDS region
    __syncthreads();  // all wt reads done
#pragma unroll
    for (int r = 0; r < 4; r++) {
        int row = wv * 16 + (lane >> 4) * 4 + r;
#pragma unroll
        for (int nf = 0; nf < 8; nf++) {
            int col = nf * 16 + (lane & 15);
            *(f16*)(lds + SWZ(row, col * 2)) = (f16)acc[nf][r];
        }
    }
    __syncthreads();

    // a_src[n,h] = sum_c xp[n,h*32+c]*att[h*32+c]; a_dst with att[128+..]
    {
        int row = t >> 2, h = t & 3;        // 64 rows x 4 heads = 256 threads
        int grow = node0 + row;
        if (grow < n) {
            float s = 0.f, d = 0.f;
#pragma unroll
            for (int cc = 0; cc < 4; cc++) {
                f16x8 v = *(const f16x8*)(lds + SWZ(row, h * 64 + cc * 16));
#pragma unroll
                for (int j = 0; j < 8; j++) {
                    float xv = (float)v[j];
                    int c = cc * 8 + j;
                    s = fmaf(xv, att_l[h * 32 + c], s);
                    d = fmaf(xv, att_l[128 + h * 32 + c], d);
                }
            }
            a_src[(size_t)grow * HEADS + h] = s;
            a_dst[(size_t)grow * HEADS + h] = d;
        }
    }
    // write xp tile out in 4-slice layout (16B stores, NORMAL caching)
    for (int i = t; i < 1024; i += 256) {
        int row = i >> 4, kc = i & 15;
        int grow = node0 + row;
        if (grow < n) {
            u32x4 v = *(const u32x4*)(lds + SWZ(row, kc * 16));
            int slice = kc >> 2;
            *(u32x4*)(xp + ((size_t)slice * n + grow) * 32 + (kc & 3) * 8) = v;
        }
    }
}

// ---- fused sliced softmax + aggregation: block (bid&3)==s, slice s==head s ----
// Round-robin dispatch puts slice-s blocks on XCDs {s, s+4}; each XCD's L2
// caches most of its 6.4 MB slice. Wave = 8 nodes.
// Phase 1 lane=(nd=lane>>3, e=lane&7): col_ind is exactly one load; gather
// a_src[ci][s] (4 B, 1.6 MB L2-resident table), softmax in 8-lane edge group.
// xp row-gathers depend only on ci, so they issue BEFORE the softmax chain.
// Phase 2 lane=(nd, c=lane&7): broadcast-shuffle alpha, in-register edge sum.
__global__ __launch_bounds__(256) void gat_slice_aggr(
    const f16* __restrict__ xp, const float* __restrict__ a_src,
    const float* __restrict__ a_dst, const int* __restrict__ row_ptr,
    const int* __restrict__ col_ind, const float* __restrict__ bias,
    float* __restrict__ out, int n, int e_total) {
    const int slice = blockIdx.x & 3;     // == head
    const int chunk = blockIdx.x >> 2;
    const int lane = threadIdx.x & 63;
    const int nb = chunk * 32 + (threadIdx.x >> 6) * 8;   // wave's base node
    if (nb >= n) return;

    const f16* xps = xp + (size_t)slice * n * 32;
    const int nd = lane >> 3, x8 = lane & 7;   // x8 = edge (ph.1) / col-oct (ph.2)
    const int node = nb + nd;

    // upfront independent loads
    int rp = 0;
    if (lane < 9) {
        int idx = nb + lane;
        if (idx > n) idx = n;
        rp = row_ptr[idx];
    }
    int ci = 0;
    {
        long long si = (long long)nb * 8 + lane;
        if (si < e_total) ci = col_ind[si];
    }
    float4 b4 = *(const float4*)(bias + slice * 32 + x8 * 4);

    bool ok = __all((lane < 9) ? (rp == (nb + lane) * 8) : 1) && (nb + 8 <= n);
    bool valid = true;
    if (!ok) {  // cold path: generic degrees (never taken for this graph)
        int rs = __shfl(rp, nd, 64), re = __shfl(rp, nd + 1, 64);
        int dg = re - rs;
        if (dg > 8) dg = 8;
        if (node >= n) dg = 0;
        valid = x8 < dg;
        ci = valid ? col_ind[rs + x8] : 0;
    }

    // xp gathers: only depend on ci broadcasts -> fly under the softmax
    f16x4 pv[8];
#pragma unroll
    for (int e = 0; e < 8; e++) {
        int src = __shfl(ci, nd * 8 + e, 64);
        pv[e] = *(const f16x4*)(xps + (size_t)src * 32 + x8 * 4);
    }

    // softmax for (node nd, edge x8), head = slice
    float as = valid ? a_src[(size_t)ci * HEADS + slice] : 0.f;
    float ad = (node < n) ? a_dst[(size_t)node * HEADS + slice] : 0.f;
    float z = as + ad;
    z = (z >= 0.f) ? z : NEG_SLOPE * z;
    float v = valid ? z : -1e30f;
    float m = v;
    m = fmaxf(m, __shfl_xor(m, 1, 64));
    m = fmaxf(m, __shfl_xor(m, 2, 64));
    m = fmaxf(m, __shfl_xor(m, 4, 64));
    float ex = valid ? __expf(v - m) : 0.f;
    float ss = ex;
    ss += __shfl_xor(ss, 1, 64);
    ss += __shfl_xor(ss, 2, 64);
    ss += __shfl_xor(ss, 4, 64);
    float alpha = ex * ((ss > 0.f) ? (1.f / ss) : 0.f);

    // aggregation: lane's 4 cols = slice*32 + x8*4 ..+4 of node nb+nd
    float a0 = 0.f, a1 = 0.f, a2 = 0.f, a3 = 0.f;
#pragma unroll
    for (int e = 0; e < 8; e++) {
        float a = __shfl(alpha, nd * 8 + e, 64);
        a0 = fmaf(a, (float)pv[e][0], a0);
        a1 = fmaf(a, (float)pv[e][1], a1);
        a2 = fmaf(a, (float)pv[e][2], a2);
        a3 = fmaf(a, (float)pv[e][3], a3);
    }

    if (node < n) {
        f32x4 o;
        o[0] = a0 + b4.x;
        o[1] = a1 + b4.y;
        o[2] = a2 + b4.z;
        o[3] = a3 + b4.w;
        __builtin_nontemporal_store(o, (f32x4*)(out + (size_t)node * 128 + slice * 32 + x8 * 4));
    }
}

extern "C" void kernel_launch(void* const* d_in, const int* in_sizes, int n_in,
                              void* d_out, int out_size, void* d_ws, size_t ws_size,
                              hipStream_t stream) {
    const float* x = (const float*)d_in[0];
    const int* row_ptr = (const int*)d_in[1];
    const int* col_ind = (const int*)d_in[2];
    // d_in[3] = max_num_neighbors (row_ptr is authoritative)
    const float* lin_w = (const float*)d_in[4];
    const float* att = (const float*)d_in[5];
    const float* bias = (const float*)d_in[6];
    float* out = (float*)d_out;
    const int n = in_sizes[0] / 128;
    const int e_total = in_sizes[2];

    // ws layout
    f16* xp = (f16*)d_ws;                                   // [4][n][32] f16 = n*256 B
    float* a_src = (float*)((char*)d_ws + (size_t)n * 256); // n*4 f32
    float* a_dst = a_src + (size_t)n * HEADS;               // n*4 f32
    f16* wt = (f16*)(a_dst + (size_t)n * HEADS);            // 128*128 f16

    hipLaunchKernelGGL(wt_kernel, dim3(8), dim3(256), 0, stream, lin_w, wt);
    hipLaunchKernelGGL(gat_proj_mfma, dim3((n + MB - 1) / MB), dim3(256), 0, stream,
                       x, wt, att, xp, a_src, a_dst, n);
    hipLaunchKernelGGL(gat_slice_aggr, dim3(4 * ((n + 31) / 32)), dim3(256), 0, stream,
                       xp, a_src, a_dst, row_ptr, col_ind, bias, out, n, e_total);
}

// Round 11
// 66.455 us; speedup vs baseline: 1.2609x; 1.2609x over previous
//
#include <hip/hip_runtime.h>
#include <stdint.h>

#define HEADS 4
#define NEG_SLOPE 0.2f
#define MB 128     // rows per block in projection kernel (512 threads, 8 waves)

typedef _Float16 f16;
typedef f16 f16x8 __attribute__((ext_vector_type(8)));
typedef f16 f16x4 __attribute__((ext_vector_type(4)));
typedef float f32x4 __attribute__((ext_vector_type(4)));
typedef unsigned int u32x4 __attribute__((ext_vector_type(4)));

// swizzled LDS byte offset for a [rows][128] f16 tile (256 B rows):
// XOR row bits into the 16B-slot bits to kill the 16-way bank conflict
#define SWZ(row, kb) (((row) << 8) + ((kb) ^ (((row) & 7) << 4)))

// ---- pre-kernel: w (f32 [K=128][N=128]) -> wt (f16 [N=128][K=128]) ----
__global__ __launch_bounds__(256) void wt_kernel(const float* __restrict__ w,
                                                 f16* __restrict__ wt) {
    __shared__ f16 tl[16][136];  // +8 pad
    const int b = blockIdx.x, t = threadIdx.x;
    for (int i = t; i < 2048; i += 256) {   // 128 k-rows x 16 cols of this slice
        int k = i >> 4, nl = i & 15;
        tl[nl][k] = (f16)w[k * 128 + b * 16 + nl];
    }
    __syncthreads();
    {
        int nl = t >> 4, kc = t & 15;       // 16 rows x 16 chunks = 256 threads
        f16x8 v = *(const f16x8*)&tl[nl][kc * 8];
        *(f16x8*)(wt + (b * 16 + nl) * 128 + kc * 8) = v;
    }
}

// ---- projection: xp = f16(x) @ f16(w) via MFMA + a_dst logit dot ----
// 512 threads, 8 waves, 128 rows/block. xp written in 4-slice layout:
// [4 slices of 32 cols][node][32] f16 (64 B rows = one cache line per
// edge-gather; slice s == head s). Only a_dst is materialized (a_src is
// recomputed inside the aggregation kernel from the gathered slice rows).
__global__ __launch_bounds__(512) void gat_proj_mfma(
    const float* __restrict__ x, const f16* __restrict__ wt,
    const float* __restrict__ att, f16* __restrict__ xp,
    float* __restrict__ a_dst, int n) {
    __shared__ unsigned char lds[32768];   // wt swizzled; reused for xp repack
    __shared__ float att_l[128];           // att_dst only
    const int t = threadIdx.x;
    const int node0 = blockIdx.x * MB;
    const int lane = t & 63;
    const int wv = t >> 6;                 // 0..7

    if (t < 128) att_l[t] = att[128 + t];

    // A-frags: row = node0 + wv*16 + (lane&15); kt-frag cols kt*32+(lane>>4)*8..+8
    const int arow = node0 + wv * 16 + (lane & 15);
    const bool rowok = arow < n;
    const float* xr = x + (size_t)arow * 128 + (lane >> 4) * 8;
    f16x8 afr[4];
#pragma unroll
    for (int kt = 0; kt < 4; kt++) {
        float4 a = make_float4(0.f, 0.f, 0.f, 0.f), b = a;
        if (rowok) {
            a = *(const float4*)(xr + kt * 32);
            b = *(const float4*)(xr + kt * 32 + 4);
        }
        f16x8 hv;
        hv[0] = (f16)a.x; hv[1] = (f16)a.y; hv[2] = (f16)a.z; hv[3] = (f16)a.w;
        hv[4] = (f16)b.x; hv[5] = (f16)b.y; hv[6] = (f16)b.z; hv[7] = (f16)b.w;
        afr[kt] = hv;
    }

    // stage wt (f16, [N][K]) into swizzled LDS
    for (int i = t; i < 2048; i += 512) {
        int row = i >> 4, kc = i & 15;
        uint4 v = *(const uint4*)(wt + row * 128 + kc * 8);
        *(uint4*)(lds + SWZ(row, kc * 16)) = v;
    }
    __syncthreads();

    // MFMA: wave wv owns rows wv*16..+15 (1 M-frag), all 128 cols
    f32x4 acc[8];
#pragma unroll
    for (int nf = 0; nf < 8; nf++) acc[nf] = (f32x4){0.f, 0.f, 0.f, 0.f};

#pragma unroll
    for (int kt = 0; kt < 4; kt++) {
        const int kb = kt * 64 + (lane >> 4) * 16;
#pragma unroll
        for (int nf = 0; nf < 8; nf++) {
            f16x8 bfr = *(const f16x8*)(lds + SWZ(nf * 16 + (lane & 15), kb));
            acc[nf] = __builtin_amdgcn_mfma_f32_16x16x32_f16(afr[kt], bfr, acc[nf], 0, 0, 0);
        }
    }

    // repack accumulators (f16) into the (now-free) wt LDS region (32 KB fits
    // exactly: 128 rows x 256 B)
    __syncthreads();  // all wt reads done
#pragma unroll
    for (int r = 0; r < 4; r++) {
        int row = wv * 16 + (lane >> 4) * 4 + r;
#pragma unroll
        for (int nf = 0; nf < 8; nf++) {
            int col = nf * 16 + (lane & 15);
            *(f16*)(lds + SWZ(row, col * 2)) = (f16)acc[nf][r];
        }
    }
    __syncthreads();

    // a_dst[n,h] = sum_c xp[n,h*32+c]*att_dst[h*32+c]; 128 rows x 4 heads = 512
    {
        int row = t >> 2, h = t & 3;
        int grow = node0 + row;
        if (grow < n) {
            float d = 0.f;
#pragma unroll
            for (int cc = 0; cc < 4; cc++) {
                f16x8 v = *(const f16x8*)(lds + SWZ(row, h * 64 + cc * 16));
#pragma unroll
                for (int j = 0; j < 8; j++)
                    d = fmaf((float)v[j], att_l[h * 32 + cc * 8 + j], d);
            }
            a_dst[(size_t)grow * HEADS + h] = d;
        }
    }
    // write xp tile out in 4-slice layout (16B stores, NORMAL caching: the
    // consumer relies on L2/L3 residency)
    for (int i = t; i < 2048; i += 512) {
        int row = i >> 4, kc = i & 15;
        int grow = node0 + row;
        if (grow < n) {
            u32x4 v = *(const u32x4*)(lds + SWZ(row, kc * 16));
            int slice = kc >> 2;
            *(u32x4*)(xp + ((size_t)slice * n + grow) * 32 + (kc & 3) * 8) = v;
        }
    }
}

// ---- fused sliced softmax + aggregation, a_src recomputed in-register ----
// block (bid&3)==s handles 32-col slice s (== head s); round-robin dispatch
// puts slice-s blocks on XCDs {s, s+4} whose L2s cache the 6.4 MB slice.
// Wave = 8 nodes; lane = (node nd=lane>>3, col-oct c=lane&7) THROUGHOUT.
// The ONLY random memory stream is the xp slice gather (one 64 B line/edge).
// a_src is recomputed from the gathered rows: per edge a 4-FMA dot +
// xor-1/2/4 reduce in the 8-lane group -> all 8 edge logits live in every
// lane's registers -> softmax AND aggregation are shuffle-free.
__global__ __launch_bounds__(256) void gat_slice_aggr(
    const f16* __restrict__ xp, const float* __restrict__ att,
    const float* __restrict__ a_dst, const int* __restrict__ row_ptr,
    const int* __restrict__ col_ind, const float* __restrict__ bias,
    float* __restrict__ out, int n, int e_total) {
    const int slice = blockIdx.x & 3;     // == head
    const int chunk = blockIdx.x >> 2;
    const int lane = threadIdx.x & 63;
    const int nb = chunk * 32 + (threadIdx.x >> 6) * 8;   // wave's base node
    if (nb >= n) return;

    const f16* xps = xp + (size_t)slice * n * 32;
    const int nd = lane >> 3, c = lane & 7;
    const int node = nb + nd;

    // upfront independent loads
    int rp = 0;
    if (lane < 9) {
        int idx = nb + lane;
        if (idx > n) idx = n;
        rp = row_ptr[idx];
    }
    int ci = 0;   // edge (node nd, edge c) src  [hot path]
    {
        long long si = (long long)nb * 8 + lane;
        if (si < e_total) ci = col_ind[si];
    }
    float4 att4 = *(const float4*)(att + slice * 32 + c * 4);   // att_src cols
    float4 b4 = *(const float4*)(bias + slice * 32 + c * 4);
    float ad = (node < n) ? a_dst[(size_t)node * HEADS + slice] : 0.f;

    // degree for this lane's node (hot path: 8)
    int rs_nd = __shfl(rp, nd, 64), re_nd = __shfl(rp, nd + 1, 64);
    int dg = re_nd - rs_nd;
    if (dg > 8) dg = 8;
    if (node >= n) dg = 0;

    bool ok = __all((lane < 9) ? (rp == (nb + lane) * 8) : 1) && (nb + 8 <= n);
    if (!ok) {  // cold path: re-fetch this lane's edge (never taken here)
        ci = (c < dg) ? col_ind[rs_nd + c] : 0;
    }

    // 8 xp row-gathers (64 B lines), all independent, issued back-to-back
    f16x4 pv[8];
#pragma unroll
    for (int e = 0; e < 8; e++) {
        int src = __shfl(ci, nd * 8 + e, 64);
        pv[e] = *(const f16x4*)(xps + (size_t)src * 32 + c * 4);
    }

    // recompute a_src logits: d[e] = dot(src_e row, att_src[head]) via
    // xor-1/2/4 reduce across the 8-lane col-oct group
    float d[8];
#pragma unroll
    for (int e = 0; e < 8; e++) {
        float s = fmaf((float)pv[e][0], att4.x,
                  fmaf((float)pv[e][1], att4.y,
                  fmaf((float)pv[e][2], att4.z,
                       (float)pv[e][3] * att4.w)));
        s += __shfl_xor(s, 1, 64);
        s += __shfl_xor(s, 2, 64);
        s += __shfl_xor(s, 4, 64);
        d[e] = s;   // replicated across the group
    }

    // in-register softmax over the 8 edges (every lane of the group computes
    // the same values; no cross-lane ops needed)
    float z[8];
#pragma unroll
    for (int e = 0; e < 8; e++) {
        float v = d[e] + ad;
        v = (v >= 0.f) ? v : NEG_SLOPE * v;
        z[e] = (e < dg) ? v : -1e30f;
    }
    float m = fmaxf(fmaxf(fmaxf(z[0], z[1]), fmaxf(z[2], z[3])),
                    fmaxf(fmaxf(z[4], z[5]), fmaxf(z[6], z[7])));
    float ex[8], ss = 0.f;
#pragma unroll
    for (int e = 0; e < 8; e++) {
        ex[e] = (e < dg) ? __expf(z[e] - m) : 0.f;
        ss += ex[e];
    }
    float inv = (ss > 0.f) ? (1.f / ss) : 0.f;

    // aggregation: shuffle-free in-register weighted sum
    float a0 = 0.f, a1 = 0.f, a2 = 0.f, a3 = 0.f;
#pragma unroll
    for (int e = 0; e < 8; e++) {
        float a = ex[e] * inv;
        a0 = fmaf(a, (float)pv[e][0], a0);
        a1 = fmaf(a, (float)pv[e][1], a1);
        a2 = fmaf(a, (float)pv[e][2], a2);
        a3 = fmaf(a, (float)pv[e][3], a3);
    }

    if (node < n) {
        f32x4 o;
        o[0] = a0 + b4.x;
        o[1] = a1 + b4.y;
        o[2] = a2 + b4.z;
        o[3] = a3 + b4.w;
        __builtin_nontemporal_store(o, (f32x4*)(out + (size_t)node * 128 + slice * 32 + c * 4));
    }
}

extern "C" void kernel_launch(void* const* d_in, const int* in_sizes, int n_in,
                              void* d_out, int out_size, void* d_ws, size_t ws_size,
                              hipStream_t stream) {
    const float* x = (const float*)d_in[0];
    const int* row_ptr = (const int*)d_in[1];
    const int* col_ind = (const int*)d_in[2];
    // d_in[3] = max_num_neighbors (row_ptr is authoritative)
    const float* lin_w = (const float*)d_in[4];
    const float* att = (const float*)d_in[5];
    const float* bias = (const float*)d_in[6];
    float* out = (float*)d_out;
    const int n = in_sizes[0] / 128;
    const int e_total = in_sizes[2];

    // ws layout
    f16* xp = (f16*)d_ws;                                   // [4][n][32] f16 = n*256 B
    float* a_dst = (float*)((char*)d_ws + (size_t)n * 256); // n*4 f32
    f16* wt = (f16*)(a_dst + (size_t)n * HEADS);            // 128*128 f16

    hipLaunchKernelGGL(wt_kernel, dim3(8), dim3(256), 0, stream, lin_w, wt);
    hipLaunchKernelGGL(gat_proj_mfma, dim3((n + MB - 1) / MB), dim3(512), 0, stream,
                       x, wt, att, xp, a_dst, n);
    hipLaunchKernelGGL(gat_slice_aggr, dim3(4 * ((n + 31) / 32)), dim3(256), 0, stream,
                       xp, att, a_dst, row_ptr, col_ind, bias, out, n, e_total);
}